// Round 1
// baseline (3340.990 us; speedup 1.0000x reference)
//
#include <hip/hip_runtime.h>
#include <cfloat>

// Problem constants
#define B_SZ 32768
#define K_SZ 8192
#define D_SZ 512

static constexpr float DECAY = 0.99f;
static constexpr float OMD   = 1.0f - 0.99f;   // (1 - decay) in fp32
static constexpr float EPS   = 1e-5f;

// ---------------------------------------------------------------------------
// Kernel A: row sum-of-squares. One wave per row (D=512). Results parked in
// o_zq scratch (overwritten by scatter_kernel at the end of the stream).
// ---------------------------------------------------------------------------
__global__ __launch_bounds__(256)
void rowsq_kernel(const float* __restrict__ src, float* __restrict__ dst) {
    const int wave = threadIdx.x >> 6;
    const int lane = threadIdx.x & 63;
    const int r = blockIdx.x * 4 + wave;
    const float* row = src + (size_t)r * D_SZ;
    float s = 0.f;
#pragma unroll
    for (int i = 0; i < 2; ++i) {
        float4 v = *reinterpret_cast<const float4*>(row + i * 256 + lane * 4);
        s += v.x * v.x + v.y * v.y + v.z * v.z + v.w * v.w;
    }
#pragma unroll
    for (int off = 32; off >= 1; off >>= 1) s += __shfl_xor(s, off);
    if (lane == 0) dst[r] = s;
}

// ---------------------------------------------------------------------------
// Kernel B: EMA init. o_nemcb = DECAY*ema_cb; o_ncs = DECAY*ema_cs.
// ---------------------------------------------------------------------------
__global__ __launch_bounds__(256)
void init_ema_kernel(const float* __restrict__ ema_cb,
                     const float* __restrict__ ema_cs,
                     float* __restrict__ o_nemcb,
                     float* __restrict__ o_ncs) {
    const size_t i = (size_t)blockIdx.x * 256 + threadIdx.x;  // float4 index
    float4 e = *reinterpret_cast<const float4*>(ema_cb + i * 4);
    e.x *= DECAY; e.y *= DECAY; e.z *= DECAY; e.w *= DECAY;
    *reinterpret_cast<float4*>(o_nemcb + i * 4) = e;
    if (i < K_SZ) o_ncs[i] = DECAY * ema_cs[i];
}

// ---------------------------------------------------------------------------
// Kernel 1: distance argmin.
// Grid: 256 row-blocks x 64 col-blocks (cb = blockIdx.x & 63 fast).
// Block: 256 threads = 4 waves; tile 128 rows x 128 cols; thread-tile 8x8.
//   tr = lane&15  -> rows tr*8..+7 (same for all waves)
//   col = wid*32 + (lane>>4)*8 .. +7
// LDS: zst[32][128], cst[32][128] d-major, XOR-swizzled (p = r ^ SW(d),
//   SW(d) = ((d>>2)&3)<<3). Staging transpose-writes: 2-way conflicts (free).
//   a-reads: 4-phase BW floor. b-reads: 16-lane broadcast (free).
//
// R1 restructure (VALU diet): sw has only 4 distinct values with period 16
// in d, so the 32-d chunk is FULLY unrolled as 8 groups x 4 d, the two XOR
// bases hoisted per group, and every ds_read becomes base + compile-time
// immediate offset (d*512B). Staging addresses (global ptrs + LDS write
// indices) hoisted out of the dc loop. Accumulation order is IDENTICAL to
// the previous passing kernel (sequential d, same fmaf order) -> bit-
// identical scores -> identical indices.
// ---------------------------------------------------------------------------
__global__ __launch_bounds__(256, 4)
void argmin_kernel(const float* __restrict__ z_e,
                   const float* __restrict__ codebook,
                   const float* __restrict__ c_sq,
                   const float* __restrict__ z_sq,
                   float2* __restrict__ partials)   // [B][64]
{
    __shared__ float zst[32][128];       // 16 KB  [d][r^SW(d)]
    __shared__ float cst[32][128];       // 16 KB  [d][n^SW(d)]
    __shared__ float mbuf[4][128][2];    // 4 KB   cross-wave argmin merge

    const int tid  = threadIdx.x;
    const int wid  = tid >> 6;
    const int lane = tid & 63;
    const int tr   = lane & 15;          // row group
    const int tr8  = tr * 8;
    const int c0l  = wid * 32 + (lane >> 4) * 8;   // local col base (0..120)

    const int rb = blockIdx.x >> 6;      // row block 0..255
    const int cb = blockIdx.x & 63;      // col block 0..63
    const int b0 = rb * 128;
    const int k0 = cb * 128;

    float acc[8][8];
#pragma unroll
    for (int r = 0; r < 8; ++r)
#pragma unroll
        for (int c = 0; c < 8; ++c) acc[r][c] = 0.f;

    // ---- Hoisted staging addresses (invariant across dc chunks) ----
    // lin: d4 = lin&7 (float4 within the 32-d chunk), n = lin>>3 (row).
    // Global: 8 lanes x 16 B = 128 B contiguous per row -> coalesced.
    // LDS writes: bank = (n ^ 8*(d4&3)) & 31 -> 2-way = free (m136).
    const float* gz[4];
    const float* gc[4];
    int wd[4], wp[4];
#pragma unroll
    for (int it = 0; it < 4; ++it) {
        const int lin = it * 256 + tid;
        const int d4  = lin & 7;
        const int n   = lin >> 3;
        wd[it] = d4 * 4;
        wp[it] = n ^ ((d4 & 3) << 3);    // SW(d4*4+j) == 8*(d4&3) for j<4
        gz[it] = z_e      + (size_t)(b0 + n) * D_SZ + d4 * 4;
        gc[it] = codebook + (size_t)(k0 + n) * D_SZ + d4 * 4;
    }

#pragma unroll 1
    for (int dc = 0; dc < D_SZ; dc += 32) {
        __syncthreads();   // previous chunk's readers done
#pragma unroll
        for (int it = 0; it < 4; ++it) {
            const float4 vz = *reinterpret_cast<const float4*>(gz[it] + dc);
            const float4 vc = *reinterpret_cast<const float4*>(gc[it] + dc);
            const int d0 = wd[it], p = wp[it];
            zst[d0 + 0][p] = vz.x;  cst[d0 + 0][p] = vc.x;
            zst[d0 + 1][p] = vz.y;  cst[d0 + 1][p] = vc.y;
            zst[d0 + 2][p] = vz.z;  cst[d0 + 2][p] = vc.z;
            zst[d0 + 3][p] = vz.w;  cst[d0 + 3][p] = vc.w;
        }
        __syncthreads();

        // Fully unrolled 32-d compute: 8 sw-groups x 4 d each.
        // d = g4*4 + q; SW(d) = (g4&3)<<3. xa/xb hoisted per group; every
        // ds_read is base + immediate (d*512 bytes [+16]).
#pragma unroll
        for (int g4 = 0; g4 < 8; ++g4) {
            const int xa = tr8 ^ ((g4 & 3) << 3);
            const int xb = c0l ^ ((g4 & 3) << 3);
#pragma unroll
            for (int q = 0; q < 4; ++q) {
                const int d = g4 * 4 + q;
                // physical run (x^sw)+i == logical (x+i)^sw for i<8,
                // sw multiple of 8, x multiple of 8
                const float4 a0 = *reinterpret_cast<const float4*>(&zst[d][xa]);
                const float4 a1 = *reinterpret_cast<const float4*>(&zst[d][xa + 4]);
                const float4 b0 = *reinterpret_cast<const float4*>(&cst[d][xb]);
                const float4 b1 = *reinterpret_cast<const float4*>(&cst[d][xb + 4]);
                const float av[8] = {a0.x, a0.y, a0.z, a0.w, a1.x, a1.y, a1.z, a1.w};
                const float bv[8] = {b0.x, b0.y, b0.z, b0.w, b1.x, b1.y, b1.z, b1.w};
#pragma unroll
                for (int r = 0; r < 8; ++r)
#pragma unroll
                    for (int c = 0; c < 8; ++c)
                        acc[r][c] = fmaf(av[r], bv[c], acc[r][c]);
            }
        }
    }

    // ---- Epilogue: d2 + per-row argmin over this block's 128 cols ----
    float zq[8], cq[8];
#pragma unroll
    for (int j = 0; j < 8; ++j) zq[j] = z_sq[b0 + tr8 + j];
#pragma unroll
    for (int j = 0; j < 8; ++j) cq[j] = c_sq[k0 + c0l + j];

    float mv[8];
    int   mi[8];
#pragma unroll
    for (int r = 0; r < 8; ++r) {
        mv[r] = FLT_MAX; mi[r] = 0;
#pragma unroll
        for (int c = 0; c < 8; ++c) {
            float s = fmaf(-2.f, acc[r][c], zq[r]) + cq[c];
            if (s < mv[r]) { mv[r] = s; mi[r] = k0 + c0l + c; }
        }
        // merge across the 4 col-groups of this wave (lanes tr, tr+16, +32, +48)
#pragma unroll
        for (int off = 16; off <= 32; off <<= 1) {
            float v2 = __shfl_xor(mv[r], off);
            int   i2 = __shfl_xor(mi[r], off);
            if (v2 < mv[r] || (v2 == mv[r] && i2 < mi[r])) { mv[r] = v2; mi[r] = i2; }
        }
    }
    if ((lane >> 4) == 0) {
#pragma unroll
        for (int r = 0; r < 8; ++r) {
            mbuf[wid][tr8 + r][0] = mv[r];
            mbuf[wid][tr8 + r][1] = (float)mi[r];
        }
    }
    __syncthreads();
    // merge the 4 waves (ascending wid = ascending col -> first-min semantics)
    if (tid < 128) {
        float v = mbuf[0][tid][0];
        int   idx = (int)mbuf[0][tid][1];
#pragma unroll
        for (int w = 1; w < 4; ++w) {
            float v2 = mbuf[w][tid][0];
            int   i2 = (int)mbuf[w][tid][1];
            if (v2 < v || (v2 == v && i2 < idx)) { v = v2; idx = i2; }
        }
        partials[(size_t)(b0 + tid) * 64 + cb] = make_float2(v, (float)idx);
    }
}

// ---------------------------------------------------------------------------
// Kernel 1b: reduce 64 col-block partials per row -> final index.
// One wave per row; tie-break by smaller k (numpy first-min).
// ---------------------------------------------------------------------------
__global__ __launch_bounds__(256)
void reduce_kernel(const float2* __restrict__ partials,
                   float* __restrict__ out_idx_f) {
    const int row  = blockIdx.x * 4 + (threadIdx.x >> 6);
    const int lane = threadIdx.x & 63;
    float2 p = partials[(size_t)row * 64 + lane];
    float v = p.x;
    int idx = (int)p.y;
#pragma unroll
    for (int off = 32; off >= 1; off >>= 1) {
        float v2 = __shfl_xor(v, off);
        int   i2 = __shfl_xor(idx, off);
        if (v2 < v || (v2 == v && i2 < idx)) { v = v2; idx = i2; }
    }
    if (lane == 0) out_idx_f[row] = (float)idx;
}

// ---------------------------------------------------------------------------
// Kernel 2: gather z_q + scatter EMA contributions into the outputs:
//   o_nemcb += OMD * z_e[b] (atomic); o_ncs += OMD (atomic, lane 0).
// ---------------------------------------------------------------------------
__global__ __launch_bounds__(256)
void scatter_kernel(const float* __restrict__ z_e,
                    const float* __restrict__ codebook,
                    const float* __restrict__ out_idx_f,
                    float* __restrict__ z_q,
                    float* __restrict__ o_ncs,
                    float* __restrict__ o_nemcb)
{
    const int wave = threadIdx.x >> 6;
    const int lane = threadIdx.x & 63;
    const int b = blockIdx.x * 4 + wave;
    const int idx = (int)out_idx_f[b];
#pragma unroll
    for (int i = 0; i < 2; ++i) {
        int d = i * 256 + lane * 4;
        float4 cq = *reinterpret_cast<const float4*>(
            codebook + (size_t)idx * D_SZ + d);
        *reinterpret_cast<float4*>(z_q + (size_t)b * D_SZ + d) = cq;
        float4 zv = *reinterpret_cast<const float4*>(
            z_e + (size_t)b * D_SZ + d);
        atomicAdd(o_nemcb + (size_t)idx * D_SZ + d + 0, OMD * zv.x);
        atomicAdd(o_nemcb + (size_t)idx * D_SZ + d + 1, OMD * zv.y);
        atomicAdd(o_nemcb + (size_t)idx * D_SZ + d + 2, OMD * zv.z);
        atomicAdd(o_nemcb + (size_t)idx * D_SZ + d + 3, OMD * zv.w);
    }
    if (lane == 0) atomicAdd(o_ncs + idx, OMD);
}

// ---------------------------------------------------------------------------
// Kernel 3: new_codebook = new_ema_codebook / (new_cluster_size + EPS).
// ---------------------------------------------------------------------------
__global__ __launch_bounds__(256)
void finalize_kernel(const float* __restrict__ o_nemcb,
                     const float* __restrict__ o_ncs,
                     float* __restrict__ o_ncb)
{
    const size_t i = (size_t)blockIdx.x * 256 + threadIdx.x;  // float4 index
    const int k = (int)(i >> 7);
    float4 nem = *reinterpret_cast<const float4*>(o_nemcb + i * 4);
    float den = o_ncs[k] + EPS;
    float4 ncb;
    ncb.x = nem.x / den; ncb.y = nem.y / den;
    ncb.z = nem.z / den; ncb.w = nem.w / den;
    *reinterpret_cast<float4*>(o_ncb + i * 4) = ncb;
}

// ---------------------------------------------------------------------------
extern "C" void kernel_launch(void* const* d_in, const int* in_sizes, int n_in,
                              void* d_out, int out_size, void* d_ws, size_t ws_size,
                              hipStream_t stream) {
    const float* z_e      = (const float*)d_in[0];   // (B, D)
    const float* codebook = (const float*)d_in[1];   // (K, D)
    const float* ema_cs   = (const float*)d_in[2];   // (K,)
    const float* ema_cb   = (const float*)d_in[3];   // (K, D)

    float* out = (float*)d_out;
    float* o_zq    = out;                                  // B*D
    float* o_idx   = out + (size_t)B_SZ * D_SZ;            // B
    float* o_ncb   = o_idx + B_SZ;                         // K*D
    float* o_ncs   = o_ncb + (size_t)K_SZ * D_SZ;          // K
    float* o_nemcb = o_ncs + K_SZ;                         // K*D

    // Scratch parked inside o_zq (16.78M floats; scatter_kernel overwrites
    // all of it afterwards). ZERO d_ws usage.
    //   partials: B*64 float2 = 4,194,304 floats
    //   c_sq[K], z_sq[B] after it.
    float2* w_part = (float2*)o_zq;
    float*  w_csq  = o_zq + (size_t)B_SZ * 64 * 2;
    float*  w_zsq  = w_csq + K_SZ;

    rowsq_kernel<<<K_SZ / 4, 256, 0, stream>>>(codebook, w_csq);
    rowsq_kernel<<<B_SZ / 4, 256, 0, stream>>>(z_e, w_zsq);
    init_ema_kernel<<<K_SZ * D_SZ / 4 / 256, 256, 0, stream>>>(
        ema_cb, ema_cs, o_nemcb, o_ncs);
    argmin_kernel<<<(B_SZ / 128) * (K_SZ / 128), 256, 0, stream>>>(
        z_e, codebook, w_csq, w_zsq, w_part);
    reduce_kernel<<<B_SZ / 4, 256, 0, stream>>>(w_part, o_idx);
    scatter_kernel<<<B_SZ / 4, 256, 0, stream>>>(z_e, codebook, o_idx,
                                                 o_zq, o_ncs, o_nemcb);
    finalize_kernel<<<K_SZ * D_SZ / 4 / 256, 256, 0, stream>>>(
        o_nemcb, o_ncs, o_ncb);
}

// Round 2
// 3228.441 us; speedup vs baseline: 1.0349x; 1.0349x over previous
//
#include <hip/hip_runtime.h>
#include <cfloat>

// Problem constants
#define B_SZ 32768
#define K_SZ 8192
#define D_SZ 512

static constexpr float DECAY = 0.99f;
static constexpr float OMD   = 1.0f - 0.99f;   // (1 - decay) in fp32
static constexpr float EPS   = 1e-5f;

// ---------------------------------------------------------------------------
// Kernel A: row sum-of-squares. One wave per row (D=512). Results parked in
// o_zq scratch (overwritten by scatter_kernel at the end of the stream).
// ---------------------------------------------------------------------------
__global__ __launch_bounds__(256)
void rowsq_kernel(const float* __restrict__ src, float* __restrict__ dst) {
    const int wave = threadIdx.x >> 6;
    const int lane = threadIdx.x & 63;
    const int r = blockIdx.x * 4 + wave;
    const float* row = src + (size_t)r * D_SZ;
    float s = 0.f;
#pragma unroll
    for (int i = 0; i < 2; ++i) {
        float4 v = *reinterpret_cast<const float4*>(row + i * 256 + lane * 4);
        s += v.x * v.x + v.y * v.y + v.z * v.z + v.w * v.w;
    }
#pragma unroll
    for (int off = 32; off >= 1; off >>= 1) s += __shfl_xor(s, off);
    if (lane == 0) dst[r] = s;
}

// ---------------------------------------------------------------------------
// Kernel B: EMA init. o_nemcb = DECAY*ema_cb; o_ncs = DECAY*ema_cs.
// ---------------------------------------------------------------------------
__global__ __launch_bounds__(256)
void init_ema_kernel(const float* __restrict__ ema_cb,
                     const float* __restrict__ ema_cs,
                     float* __restrict__ o_nemcb,
                     float* __restrict__ o_ncs) {
    const size_t i = (size_t)blockIdx.x * 256 + threadIdx.x;  // float4 index
    float4 e = *reinterpret_cast<const float4*>(ema_cb + i * 4);
    e.x *= DECAY; e.y *= DECAY; e.z *= DECAY; e.w *= DECAY;
    *reinterpret_cast<float4*>(o_nemcb + i * 4) = e;
    if (i < K_SZ) o_ncs[i] = DECAY * ema_cs[i];
}

// ---------------------------------------------------------------------------
// Kernel 1: distance argmin.
// Grid: 256 row-blocks x 64 col-blocks (cb = blockIdx.x & 63 fast).
// Block: 256 threads = 4 waves; tile 128 rows x 128 cols; thread-tile 8x8.
//   tr = lane&15  -> rows tr*8..+7 (same for all waves)
//   col = wid*32 + (lane>>4)*8 .. +7
//
// R2: conflict-free LDS layout. The old layout's a-read put its 16 unique
// 16B addresses into only 4 bank-groups (4-way conflict; SQ_LDS_BANK_CONFLICT
// = 3.37e8 = 17% of runtime cycles). New per-d-plane layout:
//   block b = r>>2 (16B granule) is stored at position pi = sigma(b) ^ (d>>2),
//   sigma(b) = (b>>1) + ((b&1)<<4)   (even blocks -> 0..15, odd -> 16..31)
//   float pf = pi*4 + (r&3)
// Reads (per d):
//   a0 = blocks {2*tr}   -> positions (tr^h)      -> 8 bank-slots x2 = 2-way (free)
//   a1 = blocks {2*tr+1} -> positions 16+(tr^h)   -> 2-way (free)
//   b0/b1: 4 distinct slots, 16-lane broadcast    -> conflict-free
// Staging writes (per j): bank = ((m'^d4)*4 + (n&3)), d4 spans 0..7 -> all
//   32 banks, 2 lanes each (different addresses) = 2-way (free).
// av/bv receive the same logical rows in the same order as before ->
// bit-identical accumulation -> identical indices.
// ---------------------------------------------------------------------------
__global__ __launch_bounds__(256, 4)
void argmin_kernel(const float* __restrict__ z_e,
                   const float* __restrict__ codebook,
                   const float* __restrict__ c_sq,
                   const float* __restrict__ z_sq,
                   float2* __restrict__ partials)   // [B][64]
{
    __shared__ float zst[32][128];       // 16 KB  [d][pf]
    __shared__ float cst[32][128];       // 16 KB  [d][pf]
    __shared__ float mbuf[4][128][2];    // 4 KB   cross-wave argmin merge

    const int tid  = threadIdx.x;
    const int wid  = tid >> 6;
    const int lane = tid & 63;
    const int tr   = lane & 15;          // row group
    const int tr8  = tr * 8;
    const int c0l  = wid * 32 + (lane >> 4) * 8;   // local col base (0..120)
    const int cg   = c0l >> 3;           // col block-pair index (0..15)

    const int rb = blockIdx.x >> 6;      // row block 0..255
    const int cb = blockIdx.x & 63;      // col block 0..63
    const int b0 = rb * 128;
    const int k0 = cb * 128;

    float acc[8][8];
#pragma unroll
    for (int r = 0; r < 8; ++r)
#pragma unroll
        for (int c = 0; c < 8; ++c) acc[r][c] = 0.f;

    // ---- Hoisted staging addresses (invariant across dc chunks) ----
    // lin: d4 = lin&7 (float4 within the 32-d chunk), n = lin>>3 (row).
    // Global: 8 lanes x 16 B = 128 B contiguous per row -> coalesced.
    const float* gz[4];
    const float* gc[4];
    int wd[4], wp[4];
#pragma unroll
    for (int it = 0; it < 4; ++it) {
        const int lin = it * 256 + tid;
        const int d4  = lin & 7;
        const int n   = lin >> 3;
        const int blk = n >> 2;
        const int sig = (blk >> 1) + ((blk & 1) << 4);
        wd[it] = d4 * 4;
        wp[it] = (sig ^ d4) * 4 + (n & 3);
        gz[it] = z_e      + (size_t)(b0 + n) * D_SZ + d4 * 4;
        gc[it] = codebook + (size_t)(k0 + n) * D_SZ + d4 * 4;
    }

#pragma unroll 1
    for (int dc = 0; dc < D_SZ; dc += 32) {
        __syncthreads();   // previous chunk's readers done
#pragma unroll
        for (int it = 0; it < 4; ++it) {
            const float4 vz = *reinterpret_cast<const float4*>(gz[it] + dc);
            const float4 vc = *reinterpret_cast<const float4*>(gc[it] + dc);
            const int d0 = wd[it], p = wp[it];
            zst[d0 + 0][p] = vz.x;  cst[d0 + 0][p] = vc.x;
            zst[d0 + 1][p] = vz.y;  cst[d0 + 1][p] = vc.y;
            zst[d0 + 2][p] = vz.z;  cst[d0 + 2][p] = vc.z;
            zst[d0 + 3][p] = vz.w;  cst[d0 + 3][p] = vc.w;
        }
        __syncthreads();

        // Fully unrolled 32-d compute: 8 h-groups x 4 d each (h = d>>2).
        // xa/xb hoisted per group; every ds_read is base + immediate
        // (d*512 bytes [+256]).
#pragma unroll
        for (int h = 0; h < 8; ++h) {
            const int xa = (tr ^ h) * 4;     // a0 float base; a1 at +64
            const int xb = (cg ^ h) * 4;     // b0 float base; b1 at +64
#pragma unroll
            for (int q = 0; q < 4; ++q) {
                const int d = h * 4 + q;
                const float4 a0  = *reinterpret_cast<const float4*>(&zst[d][xa]);
                const float4 a1  = *reinterpret_cast<const float4*>(&zst[d][xa + 64]);
                const float4 bb0 = *reinterpret_cast<const float4*>(&cst[d][xb]);
                const float4 bb1 = *reinterpret_cast<const float4*>(&cst[d][xb + 64]);
                const float av[8] = {a0.x, a0.y, a0.z, a0.w, a1.x, a1.y, a1.z, a1.w};
                const float bv[8] = {bb0.x, bb0.y, bb0.z, bb0.w, bb1.x, bb1.y, bb1.z, bb1.w};
#pragma unroll
                for (int r = 0; r < 8; ++r)
#pragma unroll
                    for (int c = 0; c < 8; ++c)
                        acc[r][c] = fmaf(av[r], bv[c], acc[r][c]);
            }
        }
    }

    // ---- Epilogue: d2 + per-row argmin over this block's 128 cols ----
    float zq[8], cq[8];
#pragma unroll
    for (int j = 0; j < 8; ++j) zq[j] = z_sq[b0 + tr8 + j];
#pragma unroll
    for (int j = 0; j < 8; ++j) cq[j] = c_sq[k0 + c0l + j];

    float mv[8];
    int   mi[8];
#pragma unroll
    for (int r = 0; r < 8; ++r) {
        mv[r] = FLT_MAX; mi[r] = 0;
#pragma unroll
        for (int c = 0; c < 8; ++c) {
            float s = fmaf(-2.f, acc[r][c], zq[r]) + cq[c];
            if (s < mv[r]) { mv[r] = s; mi[r] = k0 + c0l + c; }
        }
        // merge across the 4 col-groups of this wave (lanes tr, tr+16, +32, +48)
#pragma unroll
        for (int off = 16; off <= 32; off <<= 1) {
            float v2 = __shfl_xor(mv[r], off);
            int   i2 = __shfl_xor(mi[r], off);
            if (v2 < mv[r] || (v2 == mv[r] && i2 < mi[r])) { mv[r] = v2; mi[r] = i2; }
        }
    }
    if ((lane >> 4) == 0) {
#pragma unroll
        for (int r = 0; r < 8; ++r) {
            mbuf[wid][tr8 + r][0] = mv[r];
            mbuf[wid][tr8 + r][1] = (float)mi[r];
        }
    }
    __syncthreads();
    // merge the 4 waves (ascending wid = ascending col -> first-min semantics)
    if (tid < 128) {
        float v = mbuf[0][tid][0];
        int   idx = (int)mbuf[0][tid][1];
#pragma unroll
        for (int w = 1; w < 4; ++w) {
            float v2 = mbuf[w][tid][0];
            int   i2 = (int)mbuf[w][tid][1];
            if (v2 < v || (v2 == v && i2 < idx)) { v = v2; idx = i2; }
        }
        partials[(size_t)(b0 + tid) * 64 + cb] = make_float2(v, (float)idx);
    }
}

// ---------------------------------------------------------------------------
// Kernel 1b: reduce 64 col-block partials per row -> final index.
// One wave per row; tie-break by smaller k (numpy first-min).
// ---------------------------------------------------------------------------
__global__ __launch_bounds__(256)
void reduce_kernel(const float2* __restrict__ partials,
                   float* __restrict__ out_idx_f) {
    const int row  = blockIdx.x * 4 + (threadIdx.x >> 6);
    const int lane = threadIdx.x & 63;
    float2 p = partials[(size_t)row * 64 + lane];
    float v = p.x;
    int idx = (int)p.y;
#pragma unroll
    for (int off = 32; off >= 1; off >>= 1) {
        float v2 = __shfl_xor(v, off);
        int   i2 = __shfl_xor(idx, off);
        if (v2 < v || (v2 == v && i2 < idx)) { v = v2; idx = i2; }
    }
    if (lane == 0) out_idx_f[row] = (float)idx;
}

// ---------------------------------------------------------------------------
// Kernel 2: gather z_q + scatter EMA contributions into the outputs:
//   o_nemcb += OMD * z_e[b] (atomic); o_ncs += OMD (atomic, lane 0).
// ---------------------------------------------------------------------------
__global__ __launch_bounds__(256)
void scatter_kernel(const float* __restrict__ z_e,
                    const float* __restrict__ codebook,
                    const float* __restrict__ out_idx_f,
                    float* __restrict__ z_q,
                    float* __restrict__ o_ncs,
                    float* __restrict__ o_nemcb)
{
    const int wave = threadIdx.x >> 6;
    const int lane = threadIdx.x & 63;
    const int b = blockIdx.x * 4 + wave;
    const int idx = (int)out_idx_f[b];
#pragma unroll
    for (int i = 0; i < 2; ++i) {
        int d = i * 256 + lane * 4;
        float4 cq = *reinterpret_cast<const float4*>(
            codebook + (size_t)idx * D_SZ + d);
        *reinterpret_cast<float4*>(z_q + (size_t)b * D_SZ + d) = cq;
        float4 zv = *reinterpret_cast<const float4*>(
            z_e + (size_t)b * D_SZ + d);
        atomicAdd(o_nemcb + (size_t)idx * D_SZ + d + 0, OMD * zv.x);
        atomicAdd(o_nemcb + (size_t)idx * D_SZ + d + 1, OMD * zv.y);
        atomicAdd(o_nemcb + (size_t)idx * D_SZ + d + 2, OMD * zv.z);
        atomicAdd(o_nemcb + (size_t)idx * D_SZ + d + 3, OMD * zv.w);
    }
    if (lane == 0) atomicAdd(o_ncs + idx, OMD);
}

// ---------------------------------------------------------------------------
// Kernel 3: new_codebook = new_ema_codebook / (new_cluster_size + EPS).
// ---------------------------------------------------------------------------
__global__ __launch_bounds__(256)
void finalize_kernel(const float* __restrict__ o_nemcb,
                     const float* __restrict__ o_ncs,
                     float* __restrict__ o_ncb)
{
    const size_t i = (size_t)blockIdx.x * 256 + threadIdx.x;  // float4 index
    const int k = (int)(i >> 7);
    float4 nem = *reinterpret_cast<const float4*>(o_nemcb + i * 4);
    float den = o_ncs[k] + EPS;
    float4 ncb;
    ncb.x = nem.x / den; ncb.y = nem.y / den;
    ncb.z = nem.z / den; ncb.w = nem.w / den;
    *reinterpret_cast<float4*>(o_ncb + i * 4) = ncb;
}

// ---------------------------------------------------------------------------
extern "C" void kernel_launch(void* const* d_in, const int* in_sizes, int n_in,
                              void* d_out, int out_size, void* d_ws, size_t ws_size,
                              hipStream_t stream) {
    const float* z_e      = (const float*)d_in[0];   // (B, D)
    const float* codebook = (const float*)d_in[1];   // (K, D)
    const float* ema_cs   = (const float*)d_in[2];   // (K,)
    const float* ema_cb   = (const float*)d_in[3];   // (K, D)

    float* out = (float*)d_out;
    float* o_zq    = out;                                  // B*D
    float* o_idx   = out + (size_t)B_SZ * D_SZ;            // B
    float* o_ncb   = o_idx + B_SZ;                         // K*D
    float* o_ncs   = o_ncb + (size_t)K_SZ * D_SZ;          // K
    float* o_nemcb = o_ncs + K_SZ;                         // K*D

    // Scratch parked inside o_zq (16.78M floats; scatter_kernel overwrites
    // all of it afterwards). ZERO d_ws usage.
    //   partials: B*64 float2 = 4,194,304 floats
    //   c_sq[K], z_sq[B] after it.
    float2* w_part = (float2*)o_zq;
    float*  w_csq  = o_zq + (size_t)B_SZ * 64 * 2;
    float*  w_zsq  = w_csq + K_SZ;

    rowsq_kernel<<<K_SZ / 4, 256, 0, stream>>>(codebook, w_csq);
    rowsq_kernel<<<B_SZ / 4, 256, 0, stream>>>(z_e, w_zsq);
    init_ema_kernel<<<K_SZ * D_SZ / 4 / 256, 256, 0, stream>>>(
        ema_cb, ema_cs, o_nemcb, o_ncs);
    argmin_kernel<<<(B_SZ / 128) * (K_SZ / 128), 256, 0, stream>>>(
        z_e, codebook, w_csq, w_zsq, w_part);
    reduce_kernel<<<B_SZ / 4, 256, 0, stream>>>(w_part, o_idx);
    scatter_kernel<<<B_SZ / 4, 256, 0, stream>>>(z_e, codebook, o_idx,
                                                 o_zq, o_ncs, o_nemcb);
    finalize_kernel<<<K_SZ * D_SZ / 4 / 256, 256, 0, stream>>>(
        o_nemcb, o_ncs, o_ncb);
}